// Round 1
// baseline (99.898 us; speedup 1.0000x reference)
//
#include <hip/hip_runtime.h>
#include <stdint.h>

#define DEVFN __device__ __forceinline__

typedef __attribute__((ext_vector_type(8))) short s16x8;
typedef __attribute__((ext_vector_type(4))) float f32x4;

DEVFN float bf2f(uint16_t u) {
  union { uint32_t i; float f; } v; v.i = ((uint32_t)u) << 16; return v.f;
}
DEVFN uint16_t f2bf(float f) {
  union { float f; uint32_t i; } v; v.f = f;
  uint32_t u = v.i;
  return (uint16_t)((u + 0x7FFFu + ((u >> 16) & 1u)) >> 16);
}

DEVFN void gload_lds16(const void* g, void* l) {
  __builtin_amdgcn_global_load_lds(
      (const __attribute__((address_space(1))) uint32_t*)g,
      (__attribute__((address_space(3))) uint32_t*)l, 16, 0, 0);
}

// ---------------------------------------------------------------------------
// Fused prep: blocks 0..2047  : x -> Xh (hi) + XR = BN(AvgPool4) hi ONLY
//             blocks 2048..5119: Wk/Wv -> Wkvi (hi, ROW-INTERLEAVED), Wp -> Wph
// Wkvi row layout: for head h (0..31), rows h*64..h*64+31 = Wk rows h*32..,
//                  rows h*64+32..h*64+63 = Wv rows h*32.. ; so a 128-row group
//                  = [K_h0 | V_h0 | K_h1 | V_h1] -> one GEMM N-tile holds
//                  matching K and V columns for 2 heads (enables KV fusion).
// ---------------------------------------------------------------------------
__global__ __launch_bounds__(256)
void prep_kernel(const float* __restrict__ x,
                 const float* __restrict__ bn_g, const float* __restrict__ bn_b,
                 const float* __restrict__ bn_m, const float* __restrict__ bn_v,
                 const float* __restrict__ Wk, const float* __restrict__ Wv,
                 const float* __restrict__ Wp,
                 uint16_t* __restrict__ Xh,
                 uint16_t* __restrict__ XRh,
                 uint16_t* __restrict__ Wkvi,
                 uint16_t* __restrict__ Wph)
{
  const int t = threadIdx.x;
  const int bid = blockIdx.x;
  if (bid < 2048) {
    const int prow = bid;                    // pooled row: b*512 + mm
    const int c0 = t * 4;
    const size_t xbase = (size_t)prow * 4096 + c0;   // x row prow*4
    float s[4] = {0.f, 0.f, 0.f, 0.f};
#pragma unroll
    for (int r = 0; r < 4; ++r) {
      const float4 w = *(const float4*)(x + xbase + (size_t)r * 1024);
      const float vv[4] = { w.x, w.y, w.z, w.w };
      uint64_t wh = 0;
#pragma unroll
      for (int j = 0; j < 4; ++j) {
        wh |= ((uint64_t)f2bf(vv[j])) << (16 * j);
        s[j] += vv[j];
      }
      *(uint64_t*)(Xh + xbase + (size_t)r * 1024) = wh;
    }
    uint64_t wh = 0;
#pragma unroll
    for (int j = 0; j < 4; ++j) {
      const int c = c0 + j;
      const float y = (s[j] * 0.25f - bn_m[c]) / sqrtf(bn_v[c] + 1e-6f) * bn_g[c] + bn_b[c];
      wh |= ((uint64_t)f2bf(y)) << (16 * j);
    }
    *(uint64_t*)(XRh + (size_t)prow * 1024 + c0) = wh;
  } else {
    const int wb = bid - 2048;               // 0..3071
    const int which = wb >> 10;
    const int i = (wb & 1023) * 256 + t;     // float4 index
    const float* src = (which == 0) ? Wk : (which == 1) ? Wv : Wp;
    const float4 v = ((const float4*)src)[i];
    const float vv[4] = { v.x, v.y, v.z, v.w };
    uint64_t wh = 0;
#pragma unroll
    for (int j = 0; j < 4; ++j)
      wh |= ((uint64_t)f2bf(vv[j])) << (16 * j);
    if (which == 2) {
      ((uint64_t*)Wph)[i] = wh;
    } else {
      const int row  = i >> 8;               // 0..1023 source row
      const int col4 = i & 255;
      const int nrow = ((row >> 5) << 6) + which * 32 + (row & 31);
      ((uint64_t*)Wkvi)[(size_t)nrow * 256 + col4] = wh;
    }
  }
}

// ---------------------------------------------------------------------------
// NT GEMM (r3/r6 known-good 2-barrier structure + T1 XCD swizzle).
// C[m,n] = sum_k A[m,k]*B[n,k]; A has APARTS parts, B has BPARTS parts.
// Geometry: BN=128, BK=64.  SMALLM=false: BM=128, waves 2x2, acc[4][4].
//                           SMALLM=true : BM=64,  waves 1x4, acc[4][2].
// LDS row = 128B (8 x 16B slots); phys slot s at row r holds src slot
// s ^ (r&7); ds_read same involution -> 0 bank conflicts (r6 measured).
// EPI: 0 = fp32 C32, 1 = bf16 hi Cb0, 2 = fp32 C32 + bias
// BATCHB: B advances N*K per rows_per_batch rows of A. AMODA: A row &1023.
// ---------------------------------------------------------------------------
template<int APARTS, int BPARTS, bool BATCHB, bool AMODA, int EPI, bool KSPLIT2,
         bool SMALLM>
__global__ __launch_bounds__(256, 2)
void gemm_nt(const uint16_t* __restrict__ A0, const uint16_t* __restrict__ A1,
             const uint16_t* __restrict__ B0, const uint16_t* __restrict__ B1,
             float* __restrict__ C32, uint16_t* __restrict__ Cb0,
             const float* __restrict__ bias,
             int M, int N, int K, int rows_per_batch)
{
  constexpr int BM = SMALLM ? 64 : 128, BN = 128, BK = 64;
  constexpr int WCN = SMALLM ? 4 : 2;         // waves along N
  constexpr int WNW = BN / WCN;               // per-wave N width (32 or 64)
  constexpr int NREP = WNW / 16;              // 2 or 4
  constexpr int APASS = SMALLM ? 2 : 4;       // A staging passes (4KB each)
  __shared__ uint16_t sA[APARTS][BM * BK];
  __shared__ uint16_t sB[BPARTS][BN * BK];

  const int t = threadIdx.x;
  const int lane = t & 63;
  const int wave = t >> 6;
  const int wr = wave / WCN, wc = wave % WCN;
  const int fq = lane >> 4, fr = lane & 15;

  // T1: XCD-chunked swizzle (gridDim.x divisible by 8 for all our grids)
  const int nwg = gridDim.x;
  const int cpx = nwg >> 3;
  const int orig = blockIdx.x;
  const int swz = (orig & 7) * cpx + (orig >> 3);
  const int nbx = N >> 7;
  const int bm = (swz / nbx) * BM;
  const int bn = (swz % nbx) * BN;

  const uint16_t* Ap[2] = { A0, A1 };
  const uint16_t* Bp[2] = { B0, B1 };
  if (BATCHB) {
    const size_t boff = (size_t)(bm / rows_per_batch) * (size_t)N * (size_t)K;
    Bp[0] += boff;
    if (BPARTS > 1) Bp[1] += boff;
  }
  if (KSPLIT2) {
    const size_t half = (size_t)blockIdx.y * M * N;
    if (EPI == 1) Cb0 += half; else C32 += half;
  }

  f32x4 acc[4][NREP];
#pragma unroll
  for (int m = 0; m < 4; ++m)
#pragma unroll
    for (int n = 0; n < NREP; ++n) acc[m][n] = (f32x4)0.0f;

  const int nkt = K >> (KSPLIT2 ? 7 : 6);
  const int kt0 = KSPLIT2 ? (blockIdx.y * nkt) : 0;
  for (int kt = kt0; kt < kt0 + nkt; ++kt) {
    __syncthreads();
#pragma unroll
    for (int i = 0; i < APASS; ++i) {
      const int X = t * 16 + i * 4096;          // linear LDS byte dest
      const int r = X >> 7;                     // row (128B per row)
      const int g = ((X >> 4) & 7) ^ (r & 7);   // pre-swizzled source slot
      const int kcol = (kt << 6) + g * 8;
      const int arow = AMODA ? ((bm + r) & 1023) : (bm + r);
      const size_t srcA = (size_t)arow * K + kcol;
#pragma unroll
      for (int p = 0; p < APARTS; ++p)
        gload_lds16(Ap[p] + srcA, (char*)(&sA[p][0]) + X);
    }
#pragma unroll
    for (int i = 0; i < 4; ++i) {
      const int X = t * 16 + i * 4096;
      const int r = X >> 7;
      const int g = ((X >> 4) & 7) ^ (r & 7);
      const int kcol = (kt << 6) + g * 8;
      const size_t srcB = (size_t)(bn + r) * K + kcol;
#pragma unroll
      for (int p = 0; p < BPARTS; ++p)
        gload_lds16(Bp[p] + srcB, (char*)(&sB[p][0]) + X);
    }
    __syncthreads();
#pragma unroll
    for (int ks = 0; ks < 2; ++ks) {
      s16x8 av[APARTS][4], bv[BPARTS][NREP];
#pragma unroll
      for (int m = 0; m < 4; ++m) {
        const int ra = wr * 64 + m * 16 + fr;
        const int offA = ra * 128 + ((((ks << 2) + fq) ^ (ra & 7)) << 4);
#pragma unroll
        for (int p = 0; p < APARTS; ++p)
          av[p][m] = *(const s16x8*)((const char*)(&sA[p][0]) + offA);
      }
#pragma unroll
      for (int n = 0; n < NREP; ++n) {
        const int rb = wc * WNW + n * 16 + fr;
        const int offB = rb * 128 + ((((ks << 2) + fq) ^ (rb & 7)) << 4);
#pragma unroll
        for (int p = 0; p < BPARTS; ++p)
          bv[p][n] = *(const s16x8*)((const char*)(&sB[p][0]) + offB);
      }
#pragma unroll
      for (int m = 0; m < 4; ++m)
#pragma unroll
        for (int n = 0; n < NREP; ++n) {
          acc[m][n] = __builtin_amdgcn_mfma_f32_16x16x32_bf16(
              av[0][m], bv[0][n], acc[m][n], 0, 0, 0);
          if constexpr (BPARTS > 1)
            acc[m][n] = __builtin_amdgcn_mfma_f32_16x16x32_bf16(
                av[0][m], bv[1][n], acc[m][n], 0, 0, 0);
          if constexpr (APARTS > 1)
            acc[m][n] = __builtin_amdgcn_mfma_f32_16x16x32_bf16(
                av[1][m], bv[0][n], acc[m][n], 0, 0, 0);
        }
    }
  }

  // epilogue: C/D layout col = lane&15, row = (lane>>4)*4 + reg (m89/m91)
#pragma unroll
  for (int m = 0; m < 4; ++m) {
#pragma unroll
    for (int n = 0; n < NREP; ++n) {
#pragma unroll
      for (int j = 0; j < 4; ++j) {
        const int row = bm + wr * 64 + m * 16 + fq * 4 + j;
        const int col = bn + wc * WNW + n * 16 + fr;
        const size_t idx = (size_t)row * N + col;
        float v = acc[m][n][j];
        if constexpr (EPI == 0) {
          C32[idx] = v;
        } else if constexpr (EPI == 1) {
          Cb0[idx] = f2bf(v);
        } else {
          C32[idx] = v + bias[col];
        }
      }
    }
  }
}

// ---------------------------------------------------------------------------
// Fused KV GEMM: C = XRh @ Wkvi^T (BM=64, BN=128, full K=1024, 512 blocks),
// then per-block epilogue contracts its own C tile to KV partials:
//   part[(b*32+h)*8+ch][f][e] = sum_{64 rows} K[m,f]*V[m,e]
// Wkvi's row interleave means the block's 128 cols = [K_h0|V_h0|K_h1|V_h1]
// for heads h0 = 2*bn, h1 = 2*bn+1, so the contraction is block-local.
// K,V stay fp32 (never rounded to bf16) -> strictly better accuracy than
// the old KVcat path. Replaces old GEMM2 + kv1 (saves 32MB HBM + 1 launch).
// ---------------------------------------------------------------------------
__global__ __launch_bounds__(256, 2)
void gemm_kv(const uint16_t* __restrict__ A,   // XRh [2048][1024]
             const uint16_t* __restrict__ B,   // Wkvi [2048][1024]
             float* __restrict__ part)         // [128 bh][8 ch][32][32]
{
  constexpr int BM = 64, BN = 128, BK = 64;
  __shared__ union {
    struct { uint16_t a[BM * BK]; uint16_t b[BN * BK]; } s;   // 8KB + 16KB
    float c[BM][BN];                                          // 32KB
  } sm;

  const int t = threadIdx.x;
  const int lane = t & 63;
  const int wave = t >> 6;                  // 1x4 waves along N
  const int wc = wave;
  const int fq = lane >> 4, fr = lane & 15;

  const int nwg = gridDim.x;                // 512
  const int cpx = nwg >> 3;
  const int orig = blockIdx.x;
  const int swz = (orig & 7) * cpx + (orig >> 3);
  const int bmI = swz >> 4;                 // 0..31
  const int bnI = swz & 15;                 // 0..15
  const int bm = bmI * BM;
  const int bn = bnI * BN;

  f32x4 acc[4][2];
#pragma unroll
  for (int m = 0; m < 4; ++m)
#pragma unroll
    for (int n = 0; n < 2; ++n) acc[m][n] = (f32x4)0.0f;

  for (int kt = 0; kt < 16; ++kt) {
    __syncthreads();
#pragma unroll
    for (int i = 0; i < 2; ++i) {
      const int X = t * 16 + i * 4096;
      const int r = X >> 7;
      const int g = ((X >> 4) & 7) ^ (r & 7);
      const int kcol = (kt << 6) + g * 8;
      gload_lds16(A + (size_t)(bm + r) * 1024 + kcol, (char*)(&sm.s.a[0]) + X);
    }
#pragma unroll
    for (int i = 0; i < 4; ++i) {
      const int X = t * 16 + i * 4096;
      const int r = X >> 7;
      const int g = ((X >> 4) & 7) ^ (r & 7);
      const int kcol = (kt << 6) + g * 8;
      gload_lds16(B + (size_t)(bn + r) * 1024 + kcol, (char*)(&sm.s.b[0]) + X);
    }
    __syncthreads();
#pragma unroll
    for (int ks = 0; ks < 2; ++ks) {
      s16x8 av[4], bv[2];
#pragma unroll
      for (int m = 0; m < 4; ++m) {
        const int ra = m * 16 + fr;
        const int offA = ra * 128 + ((((ks << 2) + fq) ^ (ra & 7)) << 4);
        av[m] = *(const s16x8*)((const char*)(&sm.s.a[0]) + offA);
      }
#pragma unroll
      for (int n = 0; n < 2; ++n) {
        const int rb = wc * 32 + n * 16 + fr;
        const int offB = rb * 128 + ((((ks << 2) + fq) ^ (rb & 7)) << 4);
        bv[n] = *(const s16x8*)((const char*)(&sm.s.b[0]) + offB);
      }
#pragma unroll
      for (int m = 0; m < 4; ++m)
#pragma unroll
        for (int n = 0; n < 2; ++n)
          acc[m][n] = __builtin_amdgcn_mfma_f32_16x16x32_bf16(
              av[m], bv[n], acc[m][n], 0, 0, 0);
    }
  }

  // --- epilogue: dump fp32 C tile to LDS, contract K^T V over 64 rows ---
  __syncthreads();                          // all ds_reads of s.a/s.b done
#pragma unroll
  for (int m = 0; m < 4; ++m)
#pragma unroll
    for (int n = 0; n < 2; ++n)
#pragma unroll
      for (int j = 0; j < 4; ++j) {
        const int row = m * 16 + fq * 4 + j;
        const int col = wc * 32 + n * 16 + fr;
        sm.c[row][col] = acc[m][n][j];
      }
  __syncthreads();

  // thread -> (hsel, f, 8 e's): 2*32*4 = 256 assignments, one per thread
  const int hsel = t >> 7;                  // which of the 2 heads
  const int f  = (t >> 2) & 31;
  const int e0 = (t & 3) * 8;
  const int kcol = hsel * 64 + f;
  const int vcol = hsel * 64 + 32 + e0;
  f32x4 a0 = (f32x4)0.0f, a1 = (f32x4)0.0f;
#pragma unroll 8
  for (int m = 0; m < 64; ++m) {
    const float kf = sm.c[m][kcol];
    const f32x4 v0 = *(const f32x4*)&sm.c[m][vcol];
    const f32x4 v1 = *(const f32x4*)&sm.c[m][vcol + 4];
    a0 += v0 * kf;
    a1 += v1 * kf;
  }
  const int b = bmI >> 3, ch = bmI & 7;
  const int h = bnI * 2 + hsel;
  float* o = part + (((size_t)(b * 32 + h) * 8 + ch) * 32 + f) * 32 + e0;
  *(f32x4*)o = a0;
  *(f32x4*)(o + 4) = a1;
}

// ---------------------------------------------------------------------------
// t_kernel (kv2 fused): KV[b,h] = scale * sum_ch part[bh*8+ch];
// Tt[b][c][h*32+e] = sum_f KV[b,h][f,e] * Wq[h*32+f, c]   (bf16 hi out)
// grid: 512 blocks = (b, h, c-chunk of 256); 256 threads = one c each.
// ---------------------------------------------------------------------------
__global__ __launch_bounds__(256)
void t_kernel(const float* __restrict__ part, const float* __restrict__ Wq,
              uint16_t* __restrict__ Tth)
{
  const int bid = blockIdx.x;        // b*128 + h*4 + cc
  const int b = bid >> 7, h = (bid >> 2) & 31, cc = bid & 3;
  const int bh = b * 32 + h;
  const int t = threadIdx.x;
  __shared__ float sKV[32][32];      // [f][e]
  {
    const int f = t >> 3, e0 = (t & 7) * 4;
    f32x4 a = (f32x4)0.0f;
#pragma unroll
    for (int ch = 0; ch < 8; ++ch)
      a += *(const f32x4*)(part + ((size_t)(bh * 8 + ch) * 32 + f) * 32 + e0);
    a *= 0.17677669529663687f;       // 1/sqrt(32)
    *(f32x4*)&sKV[f][e0] = a;
  }
  __syncthreads();
  const int c = cc * 256 + t;
  f32x4 acc[8];
#pragma unroll
  for (int i = 0; i < 8; ++i) acc[i] = (f32x4)0.0f;
  const float* wqp = Wq + (size_t)(h * 32) * 1024 + c;
#pragma unroll 8
  for (int f = 0; f < 32; ++f) {
    const float wq = wqp[(size_t)f * 1024];
#pragma unroll
    for (int i = 0; i < 8; ++i) {
      const f32x4 kv = *(const f32x4*)&sKV[f][i * 4];
      acc[i] += kv * wq;
    }
  }
  const size_t o = (((size_t)b << 10) + c) * 1024 + h * 32;
#pragma unroll
  for (int i = 0; i < 8; ++i) {
    uint64_t wh = 0;
#pragma unroll
    for (int j = 0; j < 4; ++j)
      wh |= ((uint64_t)f2bf(acc[i][j])) << (16 * j);
    *(uint64_t*)(Tth + o + i * 4) = wh;
  }
}

// ---------------------------------------------------------------------------
extern "C" void kernel_launch(void* const* d_in, const int* in_sizes, int n_in,
                              void* d_out, int out_size, void* d_ws, size_t ws_size,
                              hipStream_t stream)
{
  const float* x   = (const float*)d_in[0];
  const float* Wq  = (const float*)d_in[1];
  const float* Wk  = (const float*)d_in[2];
  const float* Wv  = (const float*)d_in[3];
  const float* Wp  = (const float*)d_in[4];
  const float* bp  = (const float*)d_in[5];
  const float* bng = (const float*)d_in[6];
  const float* bnb = (const float*)d_in[7];
  const float* bnm = (const float*)d_in[8];
  const float* bnv = (const float*)d_in[9];
  float* out = (float*)d_out;

  char* ws = (char*)d_ws;
  size_t off = 0;
  auto alloc = [&](size_t bytes) {
    char* p = ws + off;
    off += (bytes + 255) & ~(size_t)255;
    return p;
  };
  uint16_t* Xh   = (uint16_t*)alloc((size_t)8192 * 1024 * 2);       // 16MB
  uint16_t* XRh  = (uint16_t*)alloc((size_t)2048 * 1024 * 2);       // 4MB
  uint16_t* Wkvi = (uint16_t*)alloc((size_t)2048 * 1024 * 2);       // 4MB
  uint16_t* Wph  = (uint16_t*)alloc((size_t)1024 * 1024 * 2);       // 2MB
  uint16_t* Tth  = (uint16_t*)alloc((size_t)4096 * 1024 * 2);       // 8MB
  uint16_t* Gh   = (uint16_t*)alloc((size_t)4096 * 1024 * 2);       // 8MB
  // overlay: KV partials (4MB) live only gemm_kv -> t_kernel, before
  // the G-GEMM writes Gh
  float* KVpart = (float*)Gh;

  // 1) fused prep: x split (hi) + XR pool/BN (hi) + weight splits (hi,
  //    Wk/Wv row-interleaved for the fused KV GEMM)
  prep_kernel<<<5120, 256, 0, stream>>>(x, bng, bnb, bnm, bnv, Wk, Wv, Wp,
                                        Xh, XRh, Wkvi, Wph);
  // 2) fused [K|V] GEMM + per-block K^T V partial contraction (replaces
  //    old GEMM2 + kv1: no 16MB KVcat round-trip, one fewer dispatch)
  gemm_kv<<<512, 256, 0, stream>>>(XRh, Wkvi, KVpart);
  // 3) Tt = (blockdiag(KV)^T Wq)^T, bf16 hi
  t_kernel<<<512, 256, 0, stream>>>(KVpart, Wq, Tth);
  // 4) G[b] = Wph @ Tt[b]^T (hh only), bf16 out, BM=64 -> 512 blocks (2/CU)
  gemm_nt<1, 1, true, true, 1, false, true><<<512, 256, 0, stream>>>(
      Wph, nullptr, Tth, nullptr, nullptr, Gh, nullptr,
      4096, 1024, 1024, 1024);
  // 5) out = Xh @ G[b]^T + bp (hh only), fp32 out
  gemm_nt<1, 1, true, false, 2, false, false><<<512, 256, 0, stream>>>(
      Xh, nullptr, Gh, nullptr, out, nullptr, bp,
      8192, 1024, 1024, 2048);
}

// Round 2
// 85.843 us; speedup vs baseline: 1.1637x; 1.1637x over previous
//
#include <hip/hip_runtime.h>
#include <stdint.h>

#define DEVFN __device__ __forceinline__

typedef __attribute__((ext_vector_type(8))) short s16x8;
typedef __attribute__((ext_vector_type(4))) float f32x4;

DEVFN float bf2f(uint16_t u) {
  union { uint32_t i; float f; } v; v.i = ((uint32_t)u) << 16; return v.f;
}
DEVFN uint16_t f2bf(float f) {
  union { float f; uint32_t i; } v; v.f = f;
  uint32_t u = v.i;
  return (uint16_t)((u + 0x7FFFu + ((u >> 16) & 1u)) >> 16);
}

DEVFN void gload_lds16(const void* g, void* l) {
  __builtin_amdgcn_global_load_lds(
      (const __attribute__((address_space(1))) uint32_t*)g,
      (__attribute__((address_space(3))) uint32_t*)l, 16, 0, 0);
}

// ---------------------------------------------------------------------------
// Fused prep: blocks 0..2047  : x -> Xh (hi) + XR = BN(AvgPool4) hi ONLY
//             blocks 2048..5119: Wk/Wv -> Wkvh (hi), Wp -> Wph (hi)
// ---------------------------------------------------------------------------
__global__ __launch_bounds__(256)
void prep_kernel(const float* __restrict__ x,
                 const float* __restrict__ bn_g, const float* __restrict__ bn_b,
                 const float* __restrict__ bn_m, const float* __restrict__ bn_v,
                 const float* __restrict__ Wk, const float* __restrict__ Wv,
                 const float* __restrict__ Wp,
                 uint16_t* __restrict__ Xh,
                 uint16_t* __restrict__ XRh,
                 uint16_t* __restrict__ Wkvh,
                 uint16_t* __restrict__ Wph)
{
  const int t = threadIdx.x;
  const int bid = blockIdx.x;
  if (bid < 2048) {
    const int prow = bid;                    // pooled row: b*512 + mm
    const int c0 = t * 4;
    const size_t xbase = (size_t)prow * 4096 + c0;   // x row prow*4
    float s[4] = {0.f, 0.f, 0.f, 0.f};
#pragma unroll
    for (int r = 0; r < 4; ++r) {
      const float4 w = *(const float4*)(x + xbase + (size_t)r * 1024);
      const float vv[4] = { w.x, w.y, w.z, w.w };
      uint64_t wh = 0;
#pragma unroll
      for (int j = 0; j < 4; ++j) {
        wh |= ((uint64_t)f2bf(vv[j])) << (16 * j);
        s[j] += vv[j];
      }
      *(uint64_t*)(Xh + xbase + (size_t)r * 1024) = wh;
    }
    uint64_t wh = 0;
#pragma unroll
    for (int j = 0; j < 4; ++j) {
      const int c = c0 + j;
      const float y = (s[j] * 0.25f - bn_m[c]) / sqrtf(bn_v[c] + 1e-6f) * bn_g[c] + bn_b[c];
      wh |= ((uint64_t)f2bf(y)) << (16 * j);
    }
    *(uint64_t*)(XRh + (size_t)prow * 1024 + c0) = wh;
  } else {
    const int wb = bid - 2048;               // 0..3071
    const int which = wb >> 10;
    const int i = (wb & 1023) * 256 + t;     // float4 index
    const float* src = (which == 0) ? Wk : (which == 1) ? Wv : Wp;
    const float4 v = ((const float4*)src)[i];
    const float vv[4] = { v.x, v.y, v.z, v.w };
    uint64_t wh = 0;
#pragma unroll
    for (int j = 0; j < 4; ++j)
      wh |= ((uint64_t)f2bf(vv[j])) << (16 * j);
    if (which == 2) {
      ((uint64_t*)Wph)[i] = wh;
    } else {
      ((uint64_t*)Wkvh)[(size_t)which * (1024 * 1024 / 4) + i] = wh;
    }
  }
}

// ---------------------------------------------------------------------------
// NT GEMM (r3/r6 known-good 2-barrier structure + T1 XCD swizzle).
// C[m,n] = sum_k A[m,k]*B[n,k]; A has APARTS parts, B has BPARTS parts.
// Geometry: BN=128, BK=128 (r2: halves the vmcnt-drain/barrier pairs vs
// BK=64 — r1 A/B showed these GEMMs are drain-bound, time ~ nkt).
//   SMALLM=false: BM=128, waves 2x2, acc[4][4], LDS 64KB -> 2 blocks/CU.
//   SMALLM=true : BM=64,  waves 1x4, acc[4][2], LDS 48KB.
// LDS row = 256B (16 x 16B slots); phys slot s at row r holds src slot
// s ^ (r&7); ds_read same involution -> 2-way/free bank pattern (m136).
// EPI: 0 = fp32 C32, 1 = bf16 hi Cb0, 2 = fp32 C32 + bias
// BATCHB: B advances N*K per rows_per_batch rows of A. AMODA: A row &1023.
// KSPLIT2: blockIdx.y in {0,1} selects K-half; C32/Cb0 += y*M*N.
// ---------------------------------------------------------------------------
template<int APARTS, int BPARTS, bool BATCHB, bool AMODA, int EPI, bool KSPLIT2,
         bool SMALLM>
__global__ __launch_bounds__(256, 2)
void gemm_nt(const uint16_t* __restrict__ A0, const uint16_t* __restrict__ A1,
             const uint16_t* __restrict__ B0, const uint16_t* __restrict__ B1,
             float* __restrict__ C32, uint16_t* __restrict__ Cb0,
             const float* __restrict__ bias,
             int M, int N, int K, int rows_per_batch)
{
  constexpr int BM = SMALLM ? 64 : 128, BN = 128, BK = 128;
  constexpr int WCN = SMALLM ? 4 : 2;         // waves along N
  constexpr int WNW = BN / WCN;               // per-wave N width (32 or 64)
  constexpr int NREP = WNW / 16;              // 2 or 4
  constexpr int APASS = SMALLM ? 4 : 8;       // A staging passes (4KB each)
  constexpr int BPASS = 8;                    // B staging passes
  __shared__ uint16_t sA[APARTS][BM * BK];
  __shared__ uint16_t sB[BPARTS][BN * BK];

  const int t = threadIdx.x;
  const int lane = t & 63;
  const int wave = t >> 6;
  const int wr = wave / WCN, wc = wave % WCN;
  const int fq = lane >> 4, fr = lane & 15;

  // T1: XCD-chunked swizzle (gridDim.x divisible by 8 for all our grids)
  const int nwg = gridDim.x;
  const int cpx = nwg >> 3;
  const int orig = blockIdx.x;
  const int swz = (orig & 7) * cpx + (orig >> 3);
  const int nbx = N >> 7;
  const int bm = (swz / nbx) * BM;
  const int bn = (swz % nbx) * BN;

  const uint16_t* Ap[2] = { A0, A1 };
  const uint16_t* Bp[2] = { B0, B1 };
  if (BATCHB) {
    const size_t boff = (size_t)(bm / rows_per_batch) * (size_t)N * (size_t)K;
    Bp[0] += boff;
    if (BPARTS > 1) Bp[1] += boff;
  }
  if (KSPLIT2) {
    const size_t half = (size_t)blockIdx.y * M * N;
    if (EPI == 1) Cb0 += half; else C32 += half;
  }

  f32x4 acc[4][NREP];
#pragma unroll
  for (int m = 0; m < 4; ++m)
#pragma unroll
    for (int n = 0; n < NREP; ++n) acc[m][n] = (f32x4)0.0f;

  const int nkt = K >> (KSPLIT2 ? 8 : 7);
  const int kt0 = KSPLIT2 ? (blockIdx.y * nkt) : 0;
  for (int kt = kt0; kt < kt0 + nkt; ++kt) {
    __syncthreads();
#pragma unroll
    for (int i = 0; i < APASS; ++i) {
      const int X = t * 16 + i * 4096;          // linear LDS byte dest
      const int r = X >> 8;                     // row (256B per row)
      const int g = ((X >> 4) & 15) ^ (r & 7);  // pre-swizzled source slot
      const int kcol = (kt << 7) + g * 8;
      const int arow = AMODA ? ((bm + r) & 1023) : (bm + r);
      const size_t srcA = (size_t)arow * K + kcol;
#pragma unroll
      for (int p = 0; p < APARTS; ++p)
        gload_lds16(Ap[p] + srcA, (char*)(&sA[p][0]) + X);
    }
#pragma unroll
    for (int i = 0; i < BPASS; ++i) {
      const int X = t * 16 + i * 4096;
      const int r = X >> 8;
      const int g = ((X >> 4) & 15) ^ (r & 7);
      const int kcol = (kt << 7) + g * 8;
      const size_t srcB = (size_t)(bn + r) * K + kcol;
#pragma unroll
      for (int p = 0; p < BPARTS; ++p)
        gload_lds16(Bp[p] + srcB, (char*)(&sB[p][0]) + X);
    }
    __syncthreads();
#pragma unroll
    for (int ks = 0; ks < 4; ++ks) {
      s16x8 av[APARTS][4], bv[BPARTS][NREP];
#pragma unroll
      for (int m = 0; m < 4; ++m) {
        const int ra = wr * 64 + m * 16 + fr;
        const int offA = ra * 256 + ((((ks << 2) + fq) ^ (ra & 7)) << 4);
#pragma unroll
        for (int p = 0; p < APARTS; ++p)
          av[p][m] = *(const s16x8*)((const char*)(&sA[p][0]) + offA);
      }
#pragma unroll
      for (int n = 0; n < NREP; ++n) {
        const int rb = wc * WNW + n * 16 + fr;
        const int offB = rb * 256 + ((((ks << 2) + fq) ^ (rb & 7)) << 4);
#pragma unroll
        for (int p = 0; p < BPARTS; ++p)
          bv[p][n] = *(const s16x8*)((const char*)(&sB[p][0]) + offB);
      }
#pragma unroll
      for (int m = 0; m < 4; ++m)
#pragma unroll
        for (int n = 0; n < NREP; ++n) {
          acc[m][n] = __builtin_amdgcn_mfma_f32_16x16x32_bf16(
              av[0][m], bv[0][n], acc[m][n], 0, 0, 0);
          if constexpr (BPARTS > 1)
            acc[m][n] = __builtin_amdgcn_mfma_f32_16x16x32_bf16(
                av[0][m], bv[1][n], acc[m][n], 0, 0, 0);
          if constexpr (APARTS > 1)
            acc[m][n] = __builtin_amdgcn_mfma_f32_16x16x32_bf16(
                av[1][m], bv[0][n], acc[m][n], 0, 0, 0);
        }
    }
  }

  // epilogue: C/D layout col = lane&15, row = (lane>>4)*4 + reg (m89/m91)
#pragma unroll
  for (int m = 0; m < 4; ++m) {
#pragma unroll
    for (int n = 0; n < NREP; ++n) {
#pragma unroll
      for (int j = 0; j < 4; ++j) {
        const int row = bm + wr * 64 + m * 16 + fq * 4 + j;
        const int col = bn + wc * WNW + n * 16 + fr;
        const size_t idx = (size_t)row * N + col;
        float v = acc[m][n][j];
        if constexpr (EPI == 0) {
          C32[idx] = v;
        } else if constexpr (EPI == 1) {
          Cb0[idx] = f2bf(v);
        } else {
          C32[idx] = v + bias[col];
        }
      }
    }
  }
}

// ---------------------------------------------------------------------------
// kv stage 1: partial[bid][f][e] = sum over 64 rows of K[.,f]*V[.,e].
// KVcat is bf16 in TWO split-K halves (stride 2048*2048); sum on stage (fp32).
// bid = bh*8 + ch. 1024 blocks -> full CU coverage.
// ---------------------------------------------------------------------------
__global__ __launch_bounds__(256)
void kv1_kernel(const uint16_t* __restrict__ KVcat, float* __restrict__ part)
{
  const int bid = blockIdx.x;
  const int bh = bid >> 3, ch = bid & 7;
  const int b = bh >> 5, h = bh & 31;
  const int t = threadIdx.x;
  __shared__ float sK[64][32];
  __shared__ float sV[64][32];
  const int f = t >> 3, e0 = (t & 7) * 4;
  const int lr = t >> 2, q = t & 3;
  const size_t rowb = (size_t)(b * 512 + ch * 64 + lr) * 2048 + h * 32 + q * 8;
  const size_t H = (size_t)2048 * 2048;   // second split-K half offset
  const s16x8 k0 = *(const s16x8*)(KVcat + rowb);
  const s16x8 k1 = *(const s16x8*)(KVcat + H + rowb);
  const s16x8 v0 = *(const s16x8*)(KVcat + rowb + 1024);
  const s16x8 v1 = *(const s16x8*)(KVcat + H + rowb + 1024);
#pragma unroll
  for (int j = 0; j < 8; ++j) {
    sK[lr][q * 8 + j] = bf2f((uint16_t)k0[j]) + bf2f((uint16_t)k1[j]);
    sV[lr][q * 8 + j] = bf2f((uint16_t)v0[j]) + bf2f((uint16_t)v1[j]);
  }
  __syncthreads();
  float a0 = 0.f, a1 = 0.f, a2 = 0.f, a3 = 0.f;
#pragma unroll 16
  for (int mm = 0; mm < 64; ++mm) {
    const float kf = sK[mm][f];
    const float4 vv = *(const float4*)&sV[mm][e0];
    a0 += kf * vv.x; a1 += kf * vv.y; a2 += kf * vv.z; a3 += kf * vv.w;
  }
  float* o = part + ((size_t)bid * 32 + f) * 32 + e0;
  o[0] = a0; o[1] = a1; o[2] = a2; o[3] = a3;
}

// ---------------------------------------------------------------------------
// t_kernel (kv2 fused): KV[b,h] = scale * sum_ch part[bh*8+ch];
// Tt[b][c][h*32+e] = sum_f KV[b,h][f,e] * Wq[h*32+f, c]   (bf16 hi out)
// grid: 512 blocks = (b, h, c-chunk of 256); 256 threads = one c each.
// ---------------------------------------------------------------------------
__global__ __launch_bounds__(256)
void t_kernel(const float* __restrict__ part, const float* __restrict__ Wq,
              uint16_t* __restrict__ Tth)
{
  const int bid = blockIdx.x;        // b*128 + h*4 + cc
  const int b = bid >> 7, h = (bid >> 2) & 31, cc = bid & 3;
  const int bh = b * 32 + h;
  const int t = threadIdx.x;
  __shared__ float sKV[32][32];      // [f][e]
  {
    const int f = t >> 3, e0 = (t & 7) * 4;
    f32x4 a = (f32x4)0.0f;
#pragma unroll
    for (int ch = 0; ch < 8; ++ch)
      a += *(const f32x4*)(part + ((size_t)(bh * 8 + ch) * 32 + f) * 32 + e0);
    a *= 0.17677669529663687f;       // 1/sqrt(32)
    *(f32x4*)&sKV[f][e0] = a;
  }
  __syncthreads();
  const int c = cc * 256 + t;
  f32x4 acc[8];
#pragma unroll
  for (int i = 0; i < 8; ++i) acc[i] = (f32x4)0.0f;
  const float* wqp = Wq + (size_t)(h * 32) * 1024 + c;
#pragma unroll 8
  for (int f = 0; f < 32; ++f) {
    const float wq = wqp[(size_t)f * 1024];
#pragma unroll
    for (int i = 0; i < 8; ++i) {
      const f32x4 kv = *(const f32x4*)&sKV[f][i * 4];
      acc[i] += kv * wq;
    }
  }
  const size_t o = (((size_t)b << 10) + c) * 1024 + h * 32;
#pragma unroll
  for (int i = 0; i < 8; ++i) {
    uint64_t wh = 0;
#pragma unroll
    for (int j = 0; j < 4; ++j)
      wh |= ((uint64_t)f2bf(acc[i][j])) << (16 * j);
    *(uint64_t*)(Tth + o + i * 4) = wh;
  }
}

// ---------------------------------------------------------------------------
extern "C" void kernel_launch(void* const* d_in, const int* in_sizes, int n_in,
                              void* d_out, int out_size, void* d_ws, size_t ws_size,
                              hipStream_t stream)
{
  const float* x   = (const float*)d_in[0];
  const float* Wq  = (const float*)d_in[1];
  const float* Wk  = (const float*)d_in[2];
  const float* Wv  = (const float*)d_in[3];
  const float* Wp  = (const float*)d_in[4];
  const float* bp  = (const float*)d_in[5];
  const float* bng = (const float*)d_in[6];
  const float* bnb = (const float*)d_in[7];
  const float* bnm = (const float*)d_in[8];
  const float* bnv = (const float*)d_in[9];
  float* out = (float*)d_out;

  char* ws = (char*)d_ws;
  size_t off = 0;
  auto alloc = [&](size_t bytes) {
    char* p = ws + off;
    off += (bytes + 255) & ~(size_t)255;
    return p;
  };
  uint16_t* Xh   = (uint16_t*)alloc((size_t)8192 * 1024 * 2);       // 16MB
  uint16_t* XRh  = (uint16_t*)alloc((size_t)2048 * 1024 * 2);       // 4MB
  uint16_t* Wkvh = (uint16_t*)alloc((size_t)2048 * 1024 * 2);       // 4MB
  uint16_t* Wph  = (uint16_t*)alloc((size_t)1024 * 1024 * 2);       // 2MB
  uint16_t* KVcat= (uint16_t*)alloc((size_t)2 * 2048 * 2048 * 2);   // 16MB (2 bf16 halves)
  uint16_t* Gh   = (uint16_t*)alloc((size_t)4096 * 1024 * 2);       // 8MB
  // overlays (lifetime-disjoint):
  // KVcat dead after kv1 -> Tth (8MB = first half)
  uint16_t* Tth = KVcat;
  // kv partials (4MB) live only kv1 -> t_kernel, before G-GEMM writes Gh
  float* KVpart = (float*)Gh;

  // 1) fused prep: x split (hi) + XR pool/BN (hi) + weight splits (hi)
  prep_kernel<<<5120, 256, 0, stream>>>(x, bng, bnb, bnm, bnv, Wk, Wv, Wp,
                                        Xh, XRh, Wkvh, Wph);
  // 2) [K|V] = XRh @ [Wk;Wv]h^T (hh only), split-K x2, bf16 partial halves
  gemm_nt<1, 1, false, false, 1, true, false><<<dim3(256, 2), 256, 0, stream>>>(
      XRh, nullptr, Wkvh, nullptr, nullptr, KVcat, nullptr,
      2048, 2048, 1024, 1 << 30);
  // 3) KV partials (sums the two bf16 split-K halves while staging)
  kv1_kernel<<<1024, 256, 0, stream>>>(KVcat, KVpart);
  // 4) Tt = (blockdiag(KV)^T Wq)^T, bf16 hi (kv2 fused; overlays KVcat)
  t_kernel<<<512, 256, 0, stream>>>(KVpart, Wq, Tth);
  // 5) G[b] = Wph @ Tt[b]^T (hh only), bf16 out, BM=64 -> 512 blocks (2/CU)
  gemm_nt<1, 1, true, true, 1, false, true><<<512, 256, 0, stream>>>(
      Wph, nullptr, Tth, nullptr, nullptr, Gh, nullptr,
      4096, 1024, 1024, 1024);
  // 6) out = Xh @ G[b]^T + bp (hh only), fp32 out
  gemm_nt<1, 1, true, false, 2, false, false><<<512, 256, 0, stream>>>(
      Xh, nullptr, Gh, nullptr, out, nullptr, bp,
      8192, 1024, 1024, 2048);
}